// Round 1
// 1245.491 us; speedup vs baseline: 1.2417x; 1.2417x over previous
//
#include <hip/hip_runtime.h>
#include <hip/hip_bf16.h>

// Problem constants (Qwen3MoeAttention: T=16384, HIDDEN=4096, TOTAL=5120)
#define T_TOK   16384
#define HID     4096
#define NTOT    5120          // Q_HID(4096) + KV_HID(512) + KV_HID(512)
#define Q_HID   4096
#define KV_END  4608          // Q_HID + KV_HID
#define HD      128           // head dim
#define EPSV    1e-6f

// GEMM geometry: 256x256 tile, BK=64, 512 threads = 8 waves (4M x 2N).
// Each wave: 64 rows x 128 cols (= one full head -> wave-local RoPE).
#define BM 256
#define BN 256
#define BK 64
#define NT (HID / BK)         // 64 K-tiles
#define THREADS 512

typedef __bf16 bf16x8 __attribute__((ext_vector_type(8)));
typedef float  f32x4  __attribute__((ext_vector_type(4)));

// ---------------------------------------------------------------------------
// fp32 -> bf16 (RNE), grid-stride, 8 elems/thread
// ---------------------------------------------------------------------------
__device__ __forceinline__ unsigned short f2bf(float f) {
    unsigned u = __builtin_bit_cast(unsigned, f);
    u += 0x7fffu + ((u >> 16) & 1u);          // RNE (inputs finite)
    return (unsigned short)(u >> 16);
}

__global__ __launch_bounds__(256)
void cvt_bf16(const float* __restrict__ in, unsigned short* __restrict__ out,
              long n) {
    const long stride = (long)gridDim.x * blockDim.x * 8;
    for (long base = 8L * (blockIdx.x * (long)blockDim.x + threadIdx.x);
         base < n; base += stride) {
        float4 v0 = *reinterpret_cast<const float4*>(in + base);
        float4 v1 = *reinterpret_cast<const float4*>(in + base + 4);
        ushort4 o0, o1;
        o0.x = f2bf(v0.x); o0.y = f2bf(v0.y); o0.z = f2bf(v0.z); o0.w = f2bf(v0.w);
        o1.x = f2bf(v1.x); o1.y = f2bf(v1.y); o1.z = f2bf(v1.z); o1.w = f2bf(v1.w);
        *reinterpret_cast<ushort4*>(out + base)     = o0;
        *reinterpret_cast<ushort4*>(out + base + 4) = o1;
    }
}

// ---------------------------------------------------------------------------
// 8-phase 256^2 GEMM (T1+T2+T3+T4+T5) + fused per-head RMSNorm + RoPE.
//
// LDS: double-buffered A,B tiles, 4 x 32 KiB = 128 KiB (dynamic).
// Swizzle (T2, involution): 16B slot within a 128B row: slot ^= (row & 7).
//   global_load_lds dest stays LINEAR; the global SOURCE is pre-permuted
//   (rule #21: linear dest + inverse-swz source + swz on read).
// Per K-tile: 4 phases x {ds_reads | stage-issue ; s_barrier ; setprio(1) ;
//   16 MFMA ; setprio(0) ; [vmcnt(8) at ph4] ; s_barrier}.
// Stage of tile t+2 is issued in ph4 (all reads of that buffer completed at
// ph3's end barrier). vmcnt(8) leaves only tile t+2's 8 loads in flight.
// ---------------------------------------------------------------------------
#define PH_BARRIER() asm volatile("s_barrier" ::: "memory")

#define STAGE(SAP, SBP, KT) do {                                              \
    const int _ko = (KT) * BK;                                                \
    _Pragma("unroll")                                                         \
    for (int s = 0; s < 4; ++s) {                                             \
        __builtin_amdgcn_global_load_lds(                                     \
            (const __attribute__((address_space(1))) void*)(Ab + off[s] + _ko),\
            (__attribute__((address_space(3))) void*)((SAP) + dst + s * 4096), \
            16, 0, 0);                                                        \
        __builtin_amdgcn_global_load_lds(                                     \
            (const __attribute__((address_space(1))) void*)(Bb + off[s] + _ko),\
            (__attribute__((address_space(3))) void*)((SBP) + dst + s * 4096), \
            16, 0, 0);                                                        \
    }                                                                         \
} while (0)

#define KTILE(SAP, SBP, TT) do {                                              \
    const char* const Al_ = (const char*)(SAP);                               \
    const char* const Bl_ = (const char*)(SBP);                               \
    bf16x8 af[4][2], bfz[4][2];                                               \
    /* ph1: read A m0-1 (4) + B n0-3 (8); MFMA (m0-1 x n0-3) */               \
    _Pragma("unroll") for (int mf = 0; mf < 2; ++mf)                          \
    _Pragma("unroll") for (int ks = 0; ks < 2; ++ks)                          \
        af[mf][ks] = *(const bf16x8*)(Al_ + aBase[ks] + mf * 2048);           \
    _Pragma("unroll") for (int nf = 0; nf < 4; ++nf)                          \
    _Pragma("unroll") for (int ks = 0; ks < 2; ++ks)                          \
        bfz[nf][ks] = *(const bf16x8*)(Bl_ + bBase[ks] + nf * 2048);          \
    PH_BARRIER();                                                             \
    __builtin_amdgcn_s_setprio(1);                                            \
    _Pragma("unroll") for (int mf = 0; mf < 2; ++mf)                          \
    _Pragma("unroll") for (int nf = 0; nf < 4; ++nf)                          \
    _Pragma("unroll") for (int ks = 0; ks < 2; ++ks)                          \
        acc[mf][nf] = __builtin_amdgcn_mfma_f32_16x16x32_bf16(                \
            af[mf][ks], bfz[nf][ks], acc[mf][nf], 0, 0, 0);                   \
    __builtin_amdgcn_s_setprio(0);                                            \
    PH_BARRIER();                                                             \
    /* ph2: read A m2-3 (4); MFMA (m2-3 x n0-3) */                            \
    _Pragma("unroll") for (int mf = 2; mf < 4; ++mf)                          \
    _Pragma("unroll") for (int ks = 0; ks < 2; ++ks)                          \
        af[mf][ks] = *(const bf16x8*)(Al_ + aBase[ks] + mf * 2048);           \
    PH_BARRIER();                                                             \
    __builtin_amdgcn_s_setprio(1);                                            \
    _Pragma("unroll") for (int mf = 2; mf < 4; ++mf)                          \
    _Pragma("unroll") for (int nf = 0; nf < 4; ++nf)                          \
    _Pragma("unroll") for (int ks = 0; ks < 2; ++ks)                          \
        acc[mf][nf] = __builtin_amdgcn_mfma_f32_16x16x32_bf16(                \
            af[mf][ks], bfz[nf][ks], acc[mf][nf], 0, 0, 0);                   \
    __builtin_amdgcn_s_setprio(0);                                            \
    PH_BARRIER();                                                             \
    /* ph3: read B n4-7 (8); MFMA (m0-1 x n4-7) */                            \
    _Pragma("unroll") for (int nf = 0; nf < 4; ++nf)                          \
    _Pragma("unroll") for (int ks = 0; ks < 2; ++ks)                          \
        bfz[nf][ks] = *(const bf16x8*)(Bl_ + bBase[ks] + (nf + 4) * 2048);    \
    PH_BARRIER();                                                             \
    __builtin_amdgcn_s_setprio(1);                                            \
    _Pragma("unroll") for (int mf = 0; mf < 2; ++mf)                          \
    _Pragma("unroll") for (int nf = 0; nf < 4; ++nf)                          \
    _Pragma("unroll") for (int ks = 0; ks < 2; ++ks)                          \
        acc[mf][nf + 4] = __builtin_amdgcn_mfma_f32_16x16x32_bf16(            \
            af[mf][ks], bfz[nf][ks], acc[mf][nf + 4], 0, 0, 0);               \
    __builtin_amdgcn_s_setprio(0);                                            \
    PH_BARRIER();                                                             \
    /* ph4: stage tile TT+2 into this buffer; MFMA (m2-3 x n4-7); fence */    \
    if ((TT) + 2 < NT) STAGE(SAP, SBP, (TT) + 2);                             \
    PH_BARRIER();                                                             \
    __builtin_amdgcn_s_setprio(1);                                            \
    _Pragma("unroll") for (int mf = 2; mf < 4; ++mf)                          \
    _Pragma("unroll") for (int nf = 0; nf < 4; ++nf)                          \
    _Pragma("unroll") for (int ks = 0; ks < 2; ++ks)                          \
        acc[mf][nf + 4] = __builtin_amdgcn_mfma_f32_16x16x32_bf16(            \
            af[mf][ks], bfz[nf][ks], acc[mf][nf + 4], 0, 0, 0);               \
    __builtin_amdgcn_s_setprio(0);                                            \
    if ((TT) + 2 < NT) { asm volatile("s_waitcnt vmcnt(8)" ::: "memory"); }   \
    else               { asm volatile("s_waitcnt vmcnt(0)" ::: "memory"); }   \
    PH_BARRIER();                                                             \
} while (0)

__global__ __launch_bounds__(THREADS)
void gemm_rmsnorm_rope(const unsigned short* __restrict__ A,   // T x HID bf16
                       const unsigned short* __restrict__ B,   // NTOT x HID bf16
                       const float* __restrict__ sinp,         // T x 128
                       const float* __restrict__ cosp,         // T x 128
                       const float* __restrict__ qw,           // 128
                       const float* __restrict__ kw,           // 128
                       float* __restrict__ out)                // T x NTOT
{
    extern __shared__ unsigned short smem[];
    unsigned short* const sA0 = smem;            // 256x64 bf16 = 32 KiB
    unsigned short* const sA1 = smem + 16384;
    unsigned short* const sB0 = smem + 32768;
    unsigned short* const sB1 = smem + 49152;

    const int tid  = threadIdx.x;
    const int wid  = tid >> 6;
    const int lane = tid & 63;
    const int l15  = lane & 15;
    const int quad = lane >> 4;
    const int wr   = wid >> 1;        // 0..3 : 64-row block within tile
    const int wc   = wid & 1;         // 0..1 : 128-col half (one head)

    // T1: XCD-aware bijective swizzle (nwg = 1280 = 8 * 160, divisible)
    const int bid = blockIdx.x;
    const int wg  = (bid & 7) * 160 + (bid >> 3);
    const int bx  = wg % 20;
    const int by  = wg / 20;
    const int m0  = by * BM;
    const int n0  = bx * BN;

    const unsigned short* __restrict__ Ab = A + (size_t)m0 * HID;
    const unsigned short* __restrict__ Bb = B + (size_t)n0 * HID;

    // Staging source offsets (pre-swizzled global addr; LDS dest linear).
    // chunk = tid + s*512 ; row = chunk>>3 ; slot' = (chunk&7) ^ (row&7)
    int off[4];
#pragma unroll
    for (int s = 0; s < 4; ++s) {
        const int chunk = tid + s * THREADS;
        const int row   = chunk >> 3;
        const int slotp = (chunk & 7) ^ (row & 7);
        off[s] = row * HID + slotp * 8;
    }
    const int dst = tid * 8;          // ushort units; + s*4096 per sweep

    // ds_read base byte offsets per k-slice (swizzled slot = slotL ^ (row&7);
    // row&7 == l15&7 since all other row terms are multiples of 16)
    int aBase[2], bBase[2];
#pragma unroll
    for (int ks = 0; ks < 2; ++ks) {
        const int sl = (((ks << 2) | quad) ^ (l15 & 7)) * 16;
        aBase[ks] = (wr * 64  + l15) * 128 + sl;
        bBase[ks] = (wc * 128 + l15) * 128 + sl;
    }

    f32x4 acc[4][8];
    const f32x4 zero = {0.f, 0.f, 0.f, 0.f};
#pragma unroll
    for (int mf = 0; mf < 4; ++mf)
#pragma unroll
        for (int nf = 0; nf < 8; ++nf) acc[mf][nf] = zero;

    // Prologue: stage tiles 0 and 1, wait for tile 0 only (counted vmcnt)
    STAGE(sA0, sB0, 0);
    STAGE(sA1, sB1, 1);
    asm volatile("s_waitcnt vmcnt(8)" ::: "memory");
    PH_BARRIER();

    for (int t = 0; t < NT; t += 2) {
        KTILE(sA0, sB0, t);
        KTILE(sA1, sB1, t + 1);
    }

    // ---------------- fused epilogue ----------------
    // C/D layout (m89-verified): col = lane&15, row = quad*4 + reg.
    // Wave rows: m0 + wr*64 + mf*16 + quad*4 + r ; cols: n0w + nf*16 + l15.
    // Each wave's 128 cols are exactly one head (n0w is 128-aligned).
    const int n0w   = n0 + wc * 128;
    const int rbase = m0 + wr * 64;
    if (n0w >= KV_END) {
        // V region: passthrough store
#pragma unroll
        for (int mf = 0; mf < 4; ++mf)
#pragma unroll
            for (int r = 0; r < 4; ++r) {
                const int row = rbase + mf * 16 + quad * 4 + r;
                float* orow = out + (size_t)row * NTOT + n0w;
#pragma unroll
                for (int nf = 0; nf < 8; ++nf)
                    orow[nf * 16 + l15] = acc[mf][nf][r];
            }
    } else {
        const float* w = (n0w < Q_HID) ? qw : kw;
        float wv[8];
#pragma unroll
        for (int nf = 0; nf < 8; ++nf) wv[nf] = w[nf * 16 + l15];

#pragma unroll
        for (int mf = 0; mf < 4; ++mf)
#pragma unroll
            for (int r = 0; r < 4; ++r) {
                const int row = rbase + mf * 16 + quad * 4 + r;
                float ss = 0.f;
#pragma unroll
                for (int nf = 0; nf < 8; ++nf) {
                    const float v = acc[mf][nf][r];
                    ss += v * v;
                }
                ss += __shfl_xor(ss, 1);
                ss += __shfl_xor(ss, 2);
                ss += __shfl_xor(ss, 4);
                ss += __shfl_xor(ss, 8);
                const float scale = rsqrtf(ss * (1.0f / 128.0f) + EPSV);

                float xn[8];
#pragma unroll
                for (int nf = 0; nf < 8; ++nf)
                    xn[nf] = acc[mf][nf][r] * scale * wv[nf];

                const float* srow = sinp + (size_t)row * HD;
                const float* crow = cosp + (size_t)row * HD;
                float* orow = out + (size_t)row * NTOT + n0w;
#pragma unroll
                for (int nf = 0; nf < 4; ++nf) {
                    const int c = nf * 16 + l15;
                    const float sv = srow[c];   // sin[c]==sin[c+64]
                    const float cv = crow[c];   // cos[c]==cos[c+64]
                    orow[c]      = xn[nf] * cv - xn[nf + 4] * sv;
                    orow[c + 64] = xn[nf] * sv + xn[nf + 4] * cv;
                }
            }
    }
}

// ---------------------------------------------------------------------------
extern "C" void kernel_launch(void* const* d_in, const int* in_sizes, int n_in,
                              void* d_out, int out_size, void* d_ws, size_t ws_size,
                              hipStream_t stream) {
    const float* hidden = (const float*)d_in[0];   // T x HID
    const float* sinp   = (const float*)d_in[1];   // T x 128
    const float* cosp   = (const float*)d_in[2];   // T x 128
    const float* w_qkv  = (const float*)d_in[3];   // NTOT x HID
    const float* qnw    = (const float*)d_in[4];   // 128
    const float* knw    = (const float*)d_in[5];   // 128
    float* out = (float*)d_out;

    // Workspace: bf16 copies of A (T x HID) then B (NTOT x HID). 176 MB.
    unsigned short* Abf = (unsigned short*)d_ws;
    unsigned short* Bbf = Abf + (size_t)T_TOK * HID;

    const long nA = (long)T_TOK * HID;     // 67,108,864
    const long nB = (long)NTOT * HID;      // 20,971,520
    cvt_bf16<<<2048, 256, 0, stream>>>(hidden, Abf, nA);
    cvt_bf16<<<1024, 256, 0, stream>>>(w_qkv, Bbf, nB);

    // 128 KiB dynamic LDS requires raising the per-kernel cap (immediate API,
    // not a stream op -> safe under graph capture).
    hipFuncSetAttribute(reinterpret_cast<const void*>(gemm_rmsnorm_rope),
                        hipFuncAttributeMaxDynamicSharedMemorySize, 131072);

    gemm_rmsnorm_rope<<<1280, THREADS, 131072, stream>>>(
        Abf, Bbf, sinp, cosp, qnw, knw, out);
}